// Round 1
// baseline (292.707 us; speedup 1.0000x reference)
//
#include <hip/hip_runtime.h>

#define NQ 8
#define KK 4
#define NLAYERS 4
#define LIN 512
#define LOUT 511            // (512 + 2*1 - 4)/1 + 1
#define BATCH 8
#define NCIRC (BATCH * LOUT)  // 4088

__device__ __forceinline__ float shx(float v, int m) {
    return __shfl_xor(v, m, 64);
}

// State layout: flat amplitude index a = lane*4 + r (a in [0,256)).
// Axis/qubit q corresponds to bit bp = 7-q of a.
//   bp>=2  -> lane bit (bp-2): cross-lane via shfl_xor
//   bp==1  -> register bit 1 (pairs (0,2),(1,3))
//   bp==0  -> register bit 0 (pairs (0,1),(2,3))

// RX(t): U = [[c, -i s], [-i s, c]]  (c=cos(t/2), s=sin(t/2))
__device__ __forceinline__ void gate_rx(float sr[4], float si[4], int bp, float c, float s, int lane) {
    if (bp >= 2) {
        const int m = 1 << (bp - 2);
        #pragma unroll
        for (int r = 0; r < 4; ++r) {
            float orr = shx(sr[r], m);
            float oii = shx(si[r], m);
            float nr = c * sr[r] + s * oii;   // new = c*mine + (-i s)*other (symmetric)
            float ni = c * si[r] - s * orr;
            sr[r] = nr; si[r] = ni;
        }
    } else if (bp == 1) {
        #pragma unroll
        for (int p = 0; p < 2; ++p) {
            const int a = p, b = p + 2;
            float ar = sr[a], ai = si[a], br = sr[b], bi = si[b];
            sr[a] = c*ar + s*bi;  si[a] = c*ai - s*br;
            sr[b] = c*br + s*ai;  si[b] = c*bi - s*ar;
        }
    } else {
        #pragma unroll
        for (int p = 0; p < 2; ++p) {
            const int a = 2*p, b = 2*p + 1;
            float ar = sr[a], ai = si[a], br = sr[b], bi = si[b];
            sr[a] = c*ar + s*bi;  si[a] = c*ai - s*br;
            sr[b] = c*br + s*ai;  si[b] = c*bi - s*ar;
        }
    }
}

// RY(t): U = [[c, -s], [s, c]]
__device__ __forceinline__ void gate_ry(float sr[4], float si[4], int bp, float c, float s, int lane) {
    if (bp >= 2) {
        const int m = 1 << (bp - 2);
        const int bit = (lane >> (bp - 2)) & 1;
        const float sg = bit ? s : -s;        // bit0: c*mine - s*other ; bit1: c*mine + s*other
        #pragma unroll
        for (int r = 0; r < 4; ++r) {
            float orr = shx(sr[r], m);
            float oii = shx(si[r], m);
            sr[r] = c * sr[r] + sg * orr;
            si[r] = c * si[r] + sg * oii;
        }
    } else if (bp == 1) {
        #pragma unroll
        for (int p = 0; p < 2; ++p) {
            const int a = p, b = p + 2;
            float ar = sr[a], ai = si[a], br = sr[b], bi = si[b];
            sr[a] = c*ar - s*br; si[a] = c*ai - s*bi;
            sr[b] = s*ar + c*br; si[b] = s*ai + c*bi;
        }
    } else {
        #pragma unroll
        for (int p = 0; p < 2; ++p) {
            const int a = 2*p, b = 2*p + 1;
            float ar = sr[a], ai = si[a], br = sr[b], bi = si[b];
            sr[a] = c*ar - s*br; si[a] = c*ai - s*bi;
            sr[b] = s*ar + c*br; si[b] = s*ai + c*bi;
        }
    }
}

// RZ(t): diag(c - i s, c + i s) — purely diagonal, never needs a shuffle
__device__ __forceinline__ void gate_rz(float sr[4], float si[4], int bp, float c, float s, int lane) {
    if (bp >= 2) {
        const int bit = (lane >> (bp - 2)) & 1;
        const float t = bit ? -s : s;
        #pragma unroll
        for (int r = 0; r < 4; ++r) {
            float nr = c * sr[r] + t * si[r];
            float ni = c * si[r] - t * sr[r];
            sr[r] = nr; si[r] = ni;
        }
    } else if (bp == 1) {
        #pragma unroll
        for (int r = 0; r < 4; ++r) {
            const float t = (r < 2) ? s : -s;
            float nr = c * sr[r] + t * si[r];
            float ni = c * si[r] - t * sr[r];
            sr[r] = nr; si[r] = ni;
        }
    } else {
        #pragma unroll
        for (int r = 0; r < 4; ++r) {
            const float t = ((r & 1) == 0) ? s : -s;
            float nr = c * sr[r] + t * si[r];
            float ni = c * si[r] - t * sr[r];
            sr[r] = nr; si[r] = ni;
        }
    }
}

// CNOT(control cq, target tq): swap target-bit pair where control bit == 1
__device__ __forceinline__ void cnot(float sr[4], float si[4], int cq, int tq, int lane) {
    const int bpc = 7 - cq, bpt = 7 - tq;
    if (bpt >= 2) {
        // both control and target are lane bits (all uses with bpt>=2 have bpc>bpt)
        const int cbit = (lane >> (bpc - 2)) & 1;
        const int m = 1 << (bpt - 2);
        #pragma unroll
        for (int r = 0; r < 4; ++r) {
            float orr = shx(sr[r], m);
            float oii = shx(si[r], m);
            sr[r] = cbit ? orr : sr[r];
            si[r] = cbit ? oii : si[r];
        }
    } else if (bpt == 1) {
        // control is a lane bit; swap (0,2),(1,3) where cbit
        const int cbit = (lane >> (bpc - 2)) & 1;
        #pragma unroll
        for (int p = 0; p < 2; ++p) {
            float t0r = sr[p], t0i = si[p];
            sr[p]   = cbit ? sr[p+2] : sr[p];
            si[p]   = cbit ? si[p+2] : si[p];
            sr[p+2] = cbit ? t0r : sr[p+2];
            si[p+2] = cbit ? t0i : si[p+2];
        }
    } else { // bpt == 0
        if (bpc == 1) {
            // register control (bit1), register target (bit0): swap indices 2,3
            float tr = sr[2], ti = si[2];
            sr[2] = sr[3]; si[2] = si[3];
            sr[3] = tr;    si[3] = ti;
        } else {
            const int cbit = (lane >> (bpc - 2)) & 1;
            #pragma unroll
            for (int p = 0; p < 2; ++p) {
                const int a = 2*p, b = 2*p + 1;
                float t0r = sr[a], t0i = si[a];
                sr[a] = cbit ? sr[b] : sr[a];
                si[a] = cbit ? si[b] : si[a];
                sr[b] = cbit ? t0r : sr[b];
                si[b] = cbit ? t0i : si[b];
            }
        }
    }
}

__device__ void ansatz(float sr[4], float si[4], const float* __restrict__ wl, int lane) {
    #pragma unroll
    for (int j = 0; j < 8; ++j) {
        const int cq = (j < 7) ? j : 0;
        const int tq = (j < 7) ? (j + 1) : 7;
        const int bp = 7 - j;
        float c, s;
        __sincosf(0.5f * wl[j*3 + 0], &s, &c);
        gate_rx(sr, si, bp, c, s, lane);
        cnot(sr, si, cq, tq, lane);
        __sincosf(0.5f * wl[j*3 + 1], &s, &c);
        gate_ry(sr, si, bp, c, s, lane);
        cnot(sr, si, cq, tq, lane);
        __sincosf(0.5f * wl[j*3 + 2], &s, &c);
        gate_rz(sr, si, bp, c, s, lane);
    }
}

__global__ __launch_bounds__(256) void quanv_kernel(const float* __restrict__ vec,
                                                    const float* __restrict__ wts,
                                                    float* __restrict__ out) {
    int wave = (int)((blockIdx.x * blockDim.x + threadIdx.x) >> 6);
    const int lane = threadIdx.x & 63;
    wave = __builtin_amdgcn_readfirstlane(wave);
    if (wave >= NCIRC) return;
    const int b = wave / LOUT;
    const int pos = wave - b * LOUT;

    // patch: padded window [pos-1, pos+2] of vec[b]
    float x[KK];
    #pragma unroll
    for (int k = 0; k < KK; ++k) {
        const int idx = pos - 1 + k;
        x[k] = (idx >= 0 && idx < LIN) ? vec[b * LIN + idx] : 0.0f;
    }

    // |0...0>
    float sr[4] = {0.f, 0.f, 0.f, 0.f};
    float si[4] = {0.f, 0.f, 0.f, 0.f};
    if (lane == 0) sr[0] = 1.0f;

    ansatz(sr, si, wts, lane);
    for (int i = 1; i <= NLAYERS; ++i) {
        // data re-upload: RY(x[k]) on qubits k and k+4
        #pragma unroll
        for (int k = 0; k < KK; ++k) {
            float c, s;
            __sincosf(0.5f * x[k], &s, &c);
            gate_ry(sr, si, 7 - k, c, s, lane);  // qubit k     -> bp 7-k (lane bit)
            gate_ry(sr, si, 3 - k, c, s, lane);  // qubit k+4   -> bp 3-k
        }
        ansatz(sr, si, wts + i * NQ * 3, lane);
    }

    // probabilities and <Z_q> partials per lane
    const float p0 = sr[0]*sr[0] + si[0]*si[0];
    const float p1 = sr[1]*sr[1] + si[1]*si[1];
    const float p2 = sr[2]*sr[2] + si[2]*si[2];
    const float p3 = sr[3]*sr[3] + si[3]*si[3];
    float z[8];
    const float pl = p0 + p1 + p2 + p3;
    #pragma unroll
    for (int q = 0; q < 6; ++q) z[q] = pl;   // sign applied during butterfly on lane bit 5-q
    z[6] = p0 + p1 - p2 - p3;                // register bit 1
    z[7] = p0 - p1 + p2 - p3;                // register bit 0

    // 6-stage signed butterfly: all lanes end with all 8 expectations
    #pragma unroll
    for (int st = 0; st < 6; ++st) {
        const int m = 1 << st;
        #pragma unroll
        for (int q = 0; q < 8; ++q) {
            float o = shx(z[q], m);
            if (q < 6 && (5 - q) == st) {
                const int bit = (lane >> st) & 1;
                z[q] = bit ? (o - z[q]) : (z[q] - o);
            } else {
                z[q] += o;
            }
        }
    }

    if (lane == 0) {
        #pragma unroll
        for (int q = 0; q < 8; ++q) {
            float v = fmaxf(z[q], 0.0f);     // relu(max) == max(relu)
            atomicMax((unsigned int*)(out + b * NQ + q), __float_as_uint(v));
        }
    }
}

__global__ void init_out_kernel(float* out) {
    if (threadIdx.x < BATCH * NQ) out[threadIdx.x] = 0.0f;
}

extern "C" void kernel_launch(void* const* d_in, const int* in_sizes, int n_in,
                              void* d_out, int out_size, void* d_ws, size_t ws_size,
                              hipStream_t stream) {
    const float* vec = (const float*)d_in[0];   // (8,1,512) float32
    const float* wts = (const float*)d_in[1];   // (5,8,3) float32
    float* out = (float*)d_out;                 // (8,8,1) float32

    hipLaunchKernelGGL(init_out_kernel, dim3(1), dim3(64), 0, stream, out);
    const int blocks = (NCIRC + 3) / 4;         // 4 waves (circuits) per 256-thread block
    hipLaunchKernelGGL(quanv_kernel, dim3(blocks), dim3(256), 0, stream, vec, wts, out);
}

// Round 2
// 75.482 us; speedup vs baseline: 3.8778x; 3.8778x over previous
//
#include <hip/hip_runtime.h>

#define NQ 8
#define KK 4
#define NLAYERS 4
#define LIN 512
#define LOUT 511            // (512 + 2*1 - 4)/1 + 1
#define BATCH 8
#define NCIRC (BATCH * LOUT)  // 4088

// Cross-launch scratch (rewritten every kernel_launch by prep_kernel; no
// reliance on d_ws size). Visibility across kernels on one stream is
// guaranteed at kernel boundaries.
__device__ float g_tab[240];   // (cos, sin) of 0.5*w for all 120 weight angles
__device__ float g_st0[512];   // state after ansatz layer 0 applied to |0..0>

// ---------------------------------------------------------------------------
// Lane-exchange: value of (lane ^ M) for compile-time M.
//   M in {1,2,3}: DPP quad_perm (pure VALU, no DS pipe)
//   M < 32     : ds_swizzle xor mode (no index VGPR needed)
//   M >= 32    : shfl (ds_bpermute, crosses 32-lane halves)
template<int M> __device__ __forceinline__ float lx(float v) {
    if constexpr (M == 1)
        return __builtin_bit_cast(float, __builtin_amdgcn_update_dpp(
            0, __builtin_bit_cast(int, v), 0xB1, 0xF, 0xF, true));   // [1,0,3,2]
    else if constexpr (M == 2)
        return __builtin_bit_cast(float, __builtin_amdgcn_update_dpp(
            0, __builtin_bit_cast(int, v), 0x4E, 0xF, 0xF, true));   // [2,3,0,1]
    else if constexpr (M == 3)
        return __builtin_bit_cast(float, __builtin_amdgcn_update_dpp(
            0, __builtin_bit_cast(int, v), 0x1B, 0xF, 0xF, true));   // [3,2,1,0]
    else if constexpr (M < 32)
        return __builtin_bit_cast(float, __builtin_amdgcn_ds_swizzle(
            __builtin_bit_cast(int, v), (M << 10) | 0x1F));          // xor mode
    else
        return __shfl_xor(v, M, 64);
}

// State layout: flat amplitude index a = lane*4 + r.  Qubit q <-> bit BP=7-q:
//   BP>=2 -> lane bit (BP-2);  BP==1 -> register bit 1;  BP==0 -> register bit 0.

// RX(t): [[c, -is], [-is, c]]
template<int BP>
__device__ __forceinline__ void g_rx(float (&sr)[4], float (&si)[4], float c, float s, int lane) {
    if constexpr (BP >= 2) {
        constexpr int M = 1 << (BP - 2);
        #pragma unroll
        for (int r = 0; r < 4; ++r) {
            float orr = lx<M>(sr[r]);
            float oii = lx<M>(si[r]);
            float nr = c * sr[r] + s * oii;
            float ni = c * si[r] - s * orr;
            sr[r] = nr; si[r] = ni;
        }
    } else if constexpr (BP == 1) {
        #pragma unroll
        for (int p = 0; p < 2; ++p) {
            const int a = p, b = p + 2;
            float ar = sr[a], ai = si[a], br = sr[b], bi = si[b];
            sr[a] = c*ar + s*bi;  si[a] = c*ai - s*br;
            sr[b] = c*br + s*ai;  si[b] = c*bi - s*ar;
        }
    } else {
        #pragma unroll
        for (int p = 0; p < 2; ++p) {
            const int a = 2*p, b = 2*p + 1;
            float ar = sr[a], ai = si[a], br = sr[b], bi = si[b];
            sr[a] = c*ar + s*bi;  si[a] = c*ai - s*br;
            sr[b] = c*br + s*ai;  si[b] = c*bi - s*ar;
        }
    }
}

// RY(t): [[c, -s], [s, c]]
template<int BP>
__device__ __forceinline__ void g_ry(float (&sr)[4], float (&si)[4], float c, float s, int lane) {
    if constexpr (BP >= 2) {
        constexpr int M = 1 << (BP - 2);
        const float sg = ((lane >> (BP - 2)) & 1) ? s : -s;
        #pragma unroll
        for (int r = 0; r < 4; ++r) {
            float orr = lx<M>(sr[r]);
            float oii = lx<M>(si[r]);
            sr[r] = c * sr[r] + sg * orr;
            si[r] = c * si[r] + sg * oii;
        }
    } else if constexpr (BP == 1) {
        #pragma unroll
        for (int p = 0; p < 2; ++p) {
            const int a = p, b = p + 2;
            float ar = sr[a], ai = si[a], br = sr[b], bi = si[b];
            sr[a] = c*ar - s*br; si[a] = c*ai - s*bi;
            sr[b] = s*ar + c*br; si[b] = s*ai + c*bi;
        }
    } else {
        #pragma unroll
        for (int p = 0; p < 2; ++p) {
            const int a = 2*p, b = 2*p + 1;
            float ar = sr[a], ai = si[a], br = sr[b], bi = si[b];
            sr[a] = c*ar - s*br; si[a] = c*ai - s*bi;
            sr[b] = s*ar + c*br; si[b] = s*ai + c*bi;
        }
    }
}

// RZ(t): diag(c - is, c + is)
template<int BP>
__device__ __forceinline__ void g_rz(float (&sr)[4], float (&si)[4], float c, float s, int lane) {
    if constexpr (BP >= 2) {
        const float t = ((lane >> (BP - 2)) & 1) ? -s : s;
        #pragma unroll
        for (int r = 0; r < 4; ++r) {
            float nr = c * sr[r] + t * si[r];
            float ni = c * si[r] - t * sr[r];
            sr[r] = nr; si[r] = ni;
        }
    } else if constexpr (BP == 1) {
        #pragma unroll
        for (int r = 0; r < 4; ++r) {
            const float t = (r < 2) ? s : -s;
            float nr = c * sr[r] + t * si[r];
            float ni = c * si[r] - t * sr[r];
            sr[r] = nr; si[r] = ni;
        }
    } else {
        #pragma unroll
        for (int r = 0; r < 4; ++r) {
            const float t = ((r & 1) == 0) ? s : -s;
            float nr = c * sr[r] + t * si[r];
            float ni = c * si[r] - t * sr[r];
            sr[r] = nr; si[r] = ni;
        }
    }
}

// Fused CNOT(c,t) . RY_c . CNOT(c,t):
//   new = cos*mine + (my_control_bit ? +sin : -sin) * partner,
//   partner = amplitude with BOTH control and target bits flipped.
template<int BPC, int BPT>
__device__ __forceinline__ void g_fry(float (&sr)[4], float (&si)[4], float c, float s, int lane) {
    if constexpr (BPT >= 2) {                       // both lane bits
        constexpr int M = (1 << (BPC - 2)) | (1 << (BPT - 2));
        const float sg = ((lane >> (BPC - 2)) & 1) ? s : -s;
        #pragma unroll
        for (int r = 0; r < 4; ++r) {
            float orr = lx<M>(sr[r]);
            float oii = lx<M>(si[r]);
            sr[r] = c * sr[r] + sg * orr;
            si[r] = c * si[r] + sg * oii;
        }
    } else if constexpr (BPT == 1) {                // control lane bit, target reg bit 1
        constexpr int M = 1 << (BPC - 2);
        const float sg = ((lane >> (BPC - 2)) & 1) ? s : -s;
        float pr[4], pi[4];
        #pragma unroll
        for (int r = 0; r < 4; ++r) { pr[r] = lx<M>(sr[r ^ 2]); pi[r] = lx<M>(si[r ^ 2]); }
        #pragma unroll
        for (int r = 0; r < 4; ++r) { sr[r] = c*sr[r] + sg*pr[r]; si[r] = c*si[r] + sg*pi[r]; }
    } else if constexpr (BPC == 1) {                // control reg bit 1, target reg bit 0
        float t0r = sr[0], t0i = si[0], t1r = sr[1], t1i = si[1];
        sr[0] = c*sr[0] - s*sr[3];  si[0] = c*si[0] - s*si[3];
        sr[1] = c*sr[1] - s*sr[2];  si[1] = c*si[1] - s*si[2];
        sr[2] = c*sr[2] + s*t1r;    si[2] = c*si[2] + s*t1i;
        sr[3] = c*sr[3] + s*t0r;    si[3] = c*si[3] + s*t0i;
    } else {                                        // control lane bit, target reg bit 0
        constexpr int M = 1 << (BPC - 2);
        const float sg = ((lane >> (BPC - 2)) & 1) ? s : -s;
        float pr[4], pi[4];
        #pragma unroll
        for (int r = 0; r < 4; ++r) { pr[r] = lx<M>(sr[r ^ 1]); pi[r] = lx<M>(si[r ^ 1]); }
        #pragma unroll
        for (int r = 0; r < 4; ++r) { sr[r] = c*sr[r] + sg*pr[r]; si[r] = c*si[r] + sg*pi[r]; }
    }
}

// One ansatz step j, trig from precomputed table t48 (48 floats = 24 (c,s) pairs).
// DROP_RZ: in the final ansatz all RZ gates commute to measurement (diagonal) -> exact skip.
template<int J, bool DROP_RZ>
__device__ __forceinline__ void astep(float (&sr)[4], float (&si)[4],
                                      const float* __restrict__ t48, int lane) {
    constexpr int CQ = (J < 7) ? J : 0;
    constexpr int TQ = (J < 7) ? (J + 1) : 7;
    constexpr int BP = 7 - J, BPC = 7 - CQ, BPT = 7 - TQ;
    g_rx<BP>(sr, si, t48[J*6 + 0], t48[J*6 + 1], lane);
    g_fry<BPC, BPT>(sr, si, t48[J*6 + 2], t48[J*6 + 3], lane);
    if constexpr (!DROP_RZ)
        g_rz<BP>(sr, si, t48[J*6 + 4], t48[J*6 + 5], lane);
}

template<bool LAST>
__device__ __forceinline__ void ansatz_t(float (&sr)[4], float (&si)[4],
                                         const float* __restrict__ t48, int lane) {
    astep<0, LAST>(sr, si, t48, lane);
    astep<1, LAST>(sr, si, t48, lane);
    astep<2, LAST>(sr, si, t48, lane);
    astep<3, LAST>(sr, si, t48, lane);
    astep<4, LAST>(sr, si, t48, lane);
    astep<5, LAST>(sr, si, t48, lane);
    astep<6, LAST>(sr, si, t48, lane);
    astep<7, LAST>(sr, si, t48, lane);
}

// Ansatz step with direct trig (prep kernel only, single wave)
template<int J>
__device__ __forceinline__ void astep0(float (&sr)[4], float (&si)[4],
                                       const float* __restrict__ wl, int lane) {
    constexpr int CQ = (J < 7) ? J : 0;
    constexpr int TQ = (J < 7) ? (J + 1) : 7;
    constexpr int BP = 7 - J, BPC = 7 - CQ, BPT = 7 - TQ;
    float a, c, s;
    a = 0.5f * wl[J*3 + 0]; s = __sinf(a); c = __cosf(a);
    g_rx<BP>(sr, si, c, s, lane);
    a = 0.5f * wl[J*3 + 1]; s = __sinf(a); c = __cosf(a);
    g_fry<BPC, BPT>(sr, si, c, s, lane);
    a = 0.5f * wl[J*3 + 2]; s = __sinf(a); c = __cosf(a);
    g_rz<BP>(sr, si, c, s, lane);
}

// Data re-upload: RY(x[k]) on qubits k and k+4 (all distinct qubits -> order free)
__device__ __forceinline__ void reup(float (&sr)[4], float (&si)[4],
                                     const float (&xc)[4], const float (&xs)[4], int lane) {
    g_ry<7>(sr, si, xc[0], xs[0], lane);  g_ry<3>(sr, si, xc[0], xs[0], lane);
    g_ry<6>(sr, si, xc[1], xs[1], lane);  g_ry<2>(sr, si, xc[1], xs[1], lane);
    g_ry<5>(sr, si, xc[2], xs[2], lane);  g_ry<1>(sr, si, xc[2], xs[2], lane);
    g_ry<4>(sr, si, xc[3], xs[3], lane);  g_ry<0>(sr, si, xc[3], xs[3], lane);
}

// Signed butterfly stage for the 8 expectation values
template<int ST>
__device__ __forceinline__ void bstage(float (&z)[8], int lane) {
    constexpr int M = 1 << ST;
    #pragma unroll
    for (int q = 0; q < 8; ++q) {
        float o = lx<M>(z[q]);
        if (q < 6 && (5 - q) == ST)
            z[q] = ((lane >> ST) & 1) ? (o - z[q]) : (z[q] - o);
        else
            z[q] += o;
    }
}

// ---------------------------------------------------------------------------
// Prep: zero out, build trig table, evolve |0..0> through ansatz layer 0.
__global__ __launch_bounds__(256) void prep_kernel(const float* __restrict__ wts,
                                                   float* __restrict__ out) {
    const int t = threadIdx.x;
    if (t >= 192) {
        const int o = t - 192;
        if (o < BATCH * NQ) out[o] = 0.0f;
    } else if (t >= 64) {
        const int o = t - 64;
        if (o < 120) {
            float a = 0.5f * wts[o];
            g_tab[2*o]     = __cosf(a);
            g_tab[2*o + 1] = __sinf(a);
        }
    } else {
        const int lane = t;
        float sr[4] = {0.f, 0.f, 0.f, 0.f};
        float si[4] = {0.f, 0.f, 0.f, 0.f};
        if (lane == 0) sr[0] = 1.0f;
        astep0<0>(sr, si, wts, lane); astep0<1>(sr, si, wts, lane);
        astep0<2>(sr, si, wts, lane); astep0<3>(sr, si, wts, lane);
        astep0<4>(sr, si, wts, lane); astep0<5>(sr, si, wts, lane);
        astep0<6>(sr, si, wts, lane); astep0<7>(sr, si, wts, lane);
        #pragma unroll
        for (int r = 0; r < 4; ++r) {
            g_st0[(lane*4 + r)*2]     = sr[r];
            g_st0[(lane*4 + r)*2 + 1] = si[r];
        }
    }
}

// ---------------------------------------------------------------------------
__global__ __launch_bounds__(256) void quanv_kernel(const float* __restrict__ vec,
                                                    float* __restrict__ out) {
    const int lane = threadIdx.x & 63;
    const int w = threadIdx.x >> 6;
    const int wave = __builtin_amdgcn_readfirstlane(blockIdx.x * 4 + w);
    const int b = wave / LOUT;
    const int pos = wave - b * LOUT;

    // patch trig (x identical across the 4 re-upload layers: compute once)
    float xc[4], xs[4];
    #pragma unroll
    for (int k = 0; k < KK; ++k) {
        int idx = pos - 1 + k;
        int ic = idx < 0 ? 0 : (idx > LIN - 1 ? LIN - 1 : idx);
        float xv = vec[b * LIN + ic];
        xv = (idx == ic) ? xv : 0.0f;        // zero-pad, clamped (in-bounds) load
        float a = 0.5f * xv;
        xs[k] = __sinf(a); xc[k] = __cosf(a);
    }

    // start from precomputed post-layer-0 state
    float sr[4], si[4];
    {
        const float4* st4 = (const float4*)g_st0;
        float4 a0 = st4[lane * 2], a1 = st4[lane * 2 + 1];
        sr[0] = a0.x; si[0] = a0.y; sr[1] = a0.z; si[1] = a0.w;
        sr[2] = a1.x; si[2] = a1.y; sr[3] = a1.z; si[3] = a1.w;
    }

    reup(sr, si, xc, xs, lane);  ansatz_t<false>(sr, si, g_tab + 1*48, lane);
    reup(sr, si, xc, xs, lane);  ansatz_t<false>(sr, si, g_tab + 2*48, lane);
    reup(sr, si, xc, xs, lane);  ansatz_t<false>(sr, si, g_tab + 3*48, lane);
    reup(sr, si, xc, xs, lane);  ansatz_t<true >(sr, si, g_tab + 4*48, lane);

    // per-lane probabilities -> <Z_q> partials
    const float p0 = sr[0]*sr[0] + si[0]*si[0];
    const float p1 = sr[1]*sr[1] + si[1]*si[1];
    const float p2 = sr[2]*sr[2] + si[2]*si[2];
    const float p3 = sr[3]*sr[3] + si[3]*si[3];
    float z[8];
    const float pl = p0 + p1 + p2 + p3;
    #pragma unroll
    for (int q = 0; q < 6; ++q) z[q] = pl;   // sign applied at butterfly stage 5-q
    z[6] = p0 + p1 - p2 - p3;                // register bit 1 (qubit 6)
    z[7] = p0 - p1 + p2 - p3;                // register bit 0 (qubit 7)

    bstage<0>(z, lane); bstage<1>(z, lane); bstage<2>(z, lane);
    bstage<3>(z, lane); bstage<4>(z, lane); bstage<5>(z, lane);

    // block-level max reduction, then one atomic per (b, q) run
    __shared__ float zsh[4][NQ];
    __shared__ int bsh[4];
    if (lane == 0) {
        bsh[w] = b;
        #pragma unroll
        for (int q = 0; q < NQ; ++q) zsh[w][q] = fmaxf(z[q], 0.0f);
    }
    __syncthreads();
    if (lane < NQ) {
        const int q = lane;
        const bool leader = (w == 0) || (bsh[w] != bsh[w - 1]);
        if (leader) {
            float m = zsh[w][q];
            for (int w2 = w + 1; w2 < 4 && bsh[w2] == bsh[w]; ++w2)
                m = fmaxf(m, zsh[w2][q]);
            atomicMax((unsigned int*)(out + bsh[w] * NQ + q), __float_as_uint(m));
        }
    }
}

extern "C" void kernel_launch(void* const* d_in, const int* in_sizes, int n_in,
                              void* d_out, int out_size, void* d_ws, size_t ws_size,
                              hipStream_t stream) {
    const float* vec = (const float*)d_in[0];   // (8,1,512) float32
    const float* wts = (const float*)d_in[1];   // (5,8,3) float32
    float* out = (float*)d_out;                 // (8,8,1) float32

    hipLaunchKernelGGL(prep_kernel, dim3(1), dim3(256), 0, stream, wts, out);
    hipLaunchKernelGGL(quanv_kernel, dim3(NCIRC / 4), dim3(256), 0, stream, vec, out);
}